// Round 13
// baseline (386.354 us; speedup 1.0000x reference)
//
#include <hip/hip_runtime.h>
#include <stdint.h>

typedef unsigned int uint;
typedef unsigned short ushort;
typedef __attribute__((ext_vector_type(4))) float f32x4;
typedef __attribute__((ext_vector_type(2))) float f32x2;
typedef __attribute__((ext_vector_type(8))) short bf16x8;   // 8 bf16 in 4 VGPRs

union U4H8 { uint4 u; bf16x8 h; };

__device__ __forceinline__ float bflo(uint u){ return __uint_as_float(u << 16); }
__device__ __forceinline__ float bfhi(uint u){ return __uint_as_float(u & 0xffff0000u); }
__device__ __forceinline__ ushort f2bf(float f){
  uint u = __float_as_uint(f);
  return (ushort)((u + 0x7fffu + ((u >> 16) & 1u)) >> 16);   // RNE
}
__device__ __forceinline__ uint pack2(float lo, float hi){
  return ((uint)f2bf(hi) << 16) | (uint)f2bf(lo);
}

// Software RNE encode f32 -> fp8 e4m3fn, f >= 0 (post-relu), saturate 448.
__device__ __forceinline__ uint fp8e(float f){
  uint u = __float_as_uint(f);
  uint r = u + 0x7FFFFu + ((u >> 20) & 1u);
  uint code = (((r >> 23) - 120u) << 3) | ((r >> 20) & 7u);
  code = (code > 0x7Eu) ? 0x7Eu : code;                  // saturate at 448
  uint den = (uint)__float2int_rn(f * 512.0f);           // 2^-9 denormal grid
  return (f >= 0.015625f) ? code : den;
}

// decode 4 fp8(e4m3) bytes of w into acc[off..off+3] (HW decode is exact)
__device__ __forceinline__ void fp8acc(float* acc, uint w, int off){
  f32x2 lo = __builtin_amdgcn_cvt_pk_f32_fp8(w, false);
  f32x2 hi = __builtin_amdgcn_cvt_pk_f32_fp8(w, true);
  acc[off+0] += lo[0]; acc[off+1] += lo[1];
  acc[off+2] += hi[0]; acc[off+3] += hi[1];
}

#define CHUNK 8192          // edges per partition block
#define NB_MU 1024          // blocks doing the mu MFMA work in the fused kernel
#define GGRID 2048          // k_gather blocks (= part rows)
#define REDB  64            // k_redC blocks (GGRID/REDB rows each)

// ---------------------------------------------------------------------------
// FUSED: MFMA GEMM #1 (mu) + edge histogram + M2 = th5 @ h_theta.
// Blocks [0,NB_MU): mu; [NB_MU, NB_MU+nblk): hist; rest: M2 rows.
// M2 block r==0 zeroes BOTH last-block counters (k_redC, k_scanHB); k_mu
// runs kernels earlier in the stream so visibility is via kernel boundary.
// ---------------------------------------------------------------------------
__global__ __launch_bounds__(256) void k_mu(
    const float* __restrict__ x, const float* __restrict__ sv,
    const float* __restrict__ tv, const float* __restrict__ th1,
    const float* __restrict__ th2, ushort* __restrict__ mu_s,
    uint2* __restrict__ mu8, int n,
    const int* __restrict__ esrc, int* __restrict__ histG, int e, int nblk,
    const float* __restrict__ th5, const float* __restrict__ hth,
    float* __restrict__ M2, int* __restrict__ ctr)
{
  __shared__ uint4 B[2048];   // [s:4][t:8][lane:64], 32 KB (mu branch)
  __shared__ int lh[256];     // hist branch
  __shared__ float m2row[128];// M2 branch
  const int tid = threadIdx.x;
  const int bid = blockIdx.x;

  if (bid >= NB_MU) {
    if (bid < NB_MU + nblk) {
      // ---- histogram branch (bucket = src>>9, layout [bucket][block]) ----
      const int blk = bid - NB_MU;
      lh[tid] = 0; __syncthreads();
      const int lo = blk*CHUNK, hi = min(e, lo + CHUNK);
      for (int i = lo + tid; i < hi; i += 256)
        atomicAdd(&lh[esrc[i] >> 9], 1);
      __syncthreads();
      histG[tid*nblk + blk] = lh[tid];
    } else {
      // ---- M2 branch: row r of th5 @ h_theta (128x256) ----
      const int r = bid - NB_MU - nblk;
      if (r == 0 && tid < 2) ctr[tid] = 0;  // reset last-block counters
      if (tid < 128) m2row[tid] = th5[r*128 + tid];
      __syncthreads();
      float accv = 0.f;
      #pragma unroll 8
      for (int k = 0; k < 128; ++k) accv += m2row[k] * hth[k*256 + tid];
      M2[r*256 + tid] = accv;
    }
    return;
  }

  // ---- mu branch (identical math; stride NB_MU*4) ----
  for (int f = tid; f < 2048; f += 256) {
    int l = f & 63, rest = f >> 6;          // rest: 0..31
    int s = rest >> 3, t = rest & 7;
    int row = t*16 + (l & 15);              // W row (output col p)
    int kb  = s*32 + (l >> 4)*8;
    const float* p = th2 + row*128 + kb;
    float4 a = *(const float4*)p;
    float4 b = *(const float4*)(p + 4);
    uint4 u; u.x = pack2(a.x,a.y); u.y = pack2(a.z,a.w);
    u.z = pack2(b.x,b.y); u.w = pack2(b.z,b.w);
    B[(s*8 + t)*64 + l] = u;
  }
  __syncthreads();
  const int w = tid >> 6, l = tid & 63, q = l >> 4, c = l & 15;
  float2 t1[8];
  #pragma unroll
  for (int t = 0; t < 8; ++t) t1[t] = ((const float2*)th1)[t*16 + c];
  const int ntiles = (n + 15) >> 4;
  for (int T = bid*4 + w; T < ntiles; T += NB_MU*4) {
    int v0 = T*16;
    int arow = min(v0 + c, n-1);
    const float4* xr = (const float4*)(x + (size_t)arow*128);
    float4 xf[8];
    #pragma unroll
    for (int s = 0; s < 4; ++s) {
      xf[2*s]   = xr[s*8 + q*2];
      xf[2*s+1] = xr[s*8 + q*2 + 1];
    }
    float ss = 0.f;
    #pragma unroll
    for (int i = 0; i < 8; ++i)
      ss += xf[i].x*xf[i].x + xf[i].y*xf[i].y + xf[i].z*xf[i].z + xf[i].w*xf[i].w;
    ss += __shfl_xor(ss, 16, 64);
    ss += __shfl_xor(ss, 32, 64);
    float inv = (ss > 0.f) ? rsqrtf(ss) : 1.f;
    U4H8 a[4];
    #pragma unroll
    for (int s = 0; s < 4; ++s) {
      float4 u0 = xf[2*s], u1 = xf[2*s+1];
      a[s].u = make_uint4(pack2(u0.x*inv, u0.y*inv), pack2(u0.z*inv, u0.w*inv),
                          pack2(u1.x*inv, u1.y*inv), pack2(u1.z*inv, u1.w*inv));
    }
    f32x4 acc[8];
    #pragma unroll
    for (int t = 0; t < 8; ++t) acc[t] = (f32x4){0.f,0.f,0.f,0.f};
    #pragma unroll
    for (int s = 0; s < 4; ++s) {
      #pragma unroll
      for (int t = 0; t < 8; ++t) {
        U4H8 b; b.u = B[(s*8 + t)*64 + l];
        acc[t] = __builtin_amdgcn_mfma_f32_16x16x32_bf16(a[s].h, b.h, acc[t], 0, 0, 0);
      }
    }
    float svr[4], tvr[4];
    #pragma unroll
    for (int r = 0; r < 4; ++r) {
      int node = min(v0 + q*4 + r, n-1);
      svr[r] = sv[node]; tvr[r] = tv[node];
    }
    #pragma unroll
    for (int r = 0; r < 4; ++r) {
      int node = v0 + q*4 + r;
      if (node < n) {
        float mm[8];
        #pragma unroll
        for (int t = 0; t < 8; ++t) {
          mm[t] = fmaxf(acc[t][r] + t1[t].x*svr[r] + t1[t].y*tvr[r], 0.f);
          mu_s[(size_t)node*128 + t*16 + c] = f2bf(mm[t]);
        }
        uint u0 = fp8e(mm[0]) | (fp8e(mm[1]) << 8) |
                  (fp8e(mm[2]) << 16) | (fp8e(mm[3]) << 24);
        uint u1 = fp8e(mm[4]) | (fp8e(mm[5]) << 8) |
                  (fp8e(mm[6]) << 16) | (fp8e(mm[7]) << 24);
        mu8[(size_t)node*16 + c] = make_uint2(u0, u1);   // bytes c*8..c*8+7
      }
    }
  }
}

// --------------------- CSR build: 2-phase bucket partition ------------------
// bucket = src>>9. Per-block ranking via LDS histogram + scan; no global
// atomic cursors. k_scanB is now FUSED into k_scanHB via the last-block
// pattern (proven in k_redC, round 12): each block scans its bucket row and
// writes btot[b]; the last-arriving block performs the 256-entry exclusive
// scan -> bucketBase. Same scan order -> bit-identical outputs. bucketBase
// stays materialized (the in-kernel-rescan CSR-trim stays retired).
// Round-9 direct-atomic CSR = 287µs k_fill (write amplification) -> retired.

__global__ __launch_bounds__(512) void k_scanHB(int* __restrict__ histG,
    int* __restrict__ bucketTot, int* __restrict__ bucketBase, int nblk,
    int* __restrict__ ctr)
{
  __shared__ int tmp[512];
  __shared__ int isLast;
  const int b = blockIdx.x, tid = threadIdx.x;
  int v = (tid < nblk) ? histG[b*nblk + tid] : 0;
  tmp[tid] = v; __syncthreads();
  for (int off = 1; off < 512; off <<= 1) {
    int t = (tid >= off) ? tmp[tid - off] : 0;
    __syncthreads();
    tmp[tid] += t;
    __syncthreads();
  }
  if (tid < nblk) histG[b*nblk + tid] = tmp[tid] - v;   // exclusive
  if (tid == nblk - 1) bucketTot[b] = tmp[tid];
  __threadfence();                        // release btot before counting in
  __syncthreads();
  if (tid == 0) isLast = (atomicAdd(ctr, 1) == gridDim.x - 1);
  __syncthreads();
  if (!isLast) return;
  __threadfence();                        // acquire: see all bucketTot writes
  // ---- scanB (identical arithmetic to the deleted kernel) ----
  int bv = (tid < 256) ? bucketTot[tid] : 0;
  tmp[tid] = bv; __syncthreads();
  for (int off = 1; off < 256; off <<= 1) {
    int t = (tid >= off && tid < 256) ? tmp[tid - off] : 0;
    __syncthreads();
    if (tid < 256) tmp[tid] += t;
    __syncthreads();
  }
  if (tid < 256) bucketBase[tid] = tmp[tid] - bv;
}

__global__ __launch_bounds__(512) void k_part(
    const int* __restrict__ src, const int* __restrict__ dst,
    const int* __restrict__ histG, const int* __restrict__ bucketBase,
    uint* __restrict__ packed, int e, int nblk)
{
  __shared__ int cur[256];
  const int blk = blockIdx.x, tid = threadIdx.x;
  if (tid < 256) cur[tid] = bucketBase[tid] + histG[tid*nblk + blk];
  __syncthreads();
  const int lo = blk*CHUNK, hi = min(e, lo + CHUNK);
  for (int i = lo + tid; i < hi; i += 512) {
    int s = src[i], d = dst[i];
    int pos = atomicAdd(&cur[s >> 9], 1);
    packed[pos] = ((uint)(s & 511) << 17) | (uint)d;
  }
}

__global__ __launch_bounds__(512) void k_csr(
    const uint* __restrict__ packed, const int* __restrict__ bucketTot,
    const int* __restrict__ bucketBase, int* __restrict__ sorted,
    int* __restrict__ rowstart, int* __restrict__ cnt, int n)
{
  __shared__ int lc[512];
  __shared__ int lofs[512];
  __shared__ int lcur[512];
  const int b = blockIdx.x, tid = threadIdx.x;
  const int base = bucketBase[b], tot = bucketTot[b];
  lc[tid] = 0; __syncthreads();
  for (int i = tid; i < tot; i += 512)
    atomicAdd(&lc[packed[base + i] >> 17], 1);
  __syncthreads();
  lofs[tid] = lc[tid]; __syncthreads();
  for (int off = 1; off < 512; off <<= 1) {
    int t = (tid >= off) ? lofs[tid - off] : 0;
    __syncthreads();
    lofs[tid] += t;
    __syncthreads();
  }
  int excl = lofs[tid] - lc[tid];
  int node = (b << 9) + tid;
  lcur[tid] = base + excl;
  if (node < n) { rowstart[node] = base + excl; cnt[node] = lc[tid]; }
  __syncthreads();
  for (int i = tid; i < tot; i += 512) {
    uint p = packed[base + i];
    int pos = atomicAdd(&lcur[p >> 17], 1);
    sorted[pos] = (int)(p & 0x1FFFFu);
  }
}

// ---------------------------------------------------------------------------
// Gather: rs[v] = relu(deg*mu[v] - sum_{u in N(v)} mu[u])  + FUSED colsum.
// EXACTLY the banked 79.5µs form (scalar acc[16], plain 8-edge loop): rounds
// 3 (4-deep, 96µs) and 5 (2-deep, 90µs) proved manual load ladders lose to
// the compiler's schedule of this loop. Do not restructure.
// All-lane epilogue: butterfly leaves full sums in every lane; lane l=g*8+c
// writes rs word l (static select tree) -> coalesced 256 B/node store;
// colsum accumulated per-lane, block-reduced to part[block][256].
// ---------------------------------------------------------------------------
__global__ __launch_bounds__(256) void k_gather(
    const uint4* __restrict__ mu8, const uint* __restrict__ mu_u,
    const int* __restrict__ sorted, const int* __restrict__ cnt,
    const int* __restrict__ rowstart, uint* __restrict__ rs_u,
    float* __restrict__ part, int n)
{
  __shared__ float ls[4*256];
  const int w = threadIdx.x >> 6, l = threadIdx.x & 63;
  const int g = l >> 3, c = l & 7;
  float cm0 = 0.f, cm1 = 0.f, cr0 = 0.f, cr1 = 0.f;   // colsum accumulators
  for (int v = blockIdx.x*4 + w; v < n; v += gridDim.x*4) {
    int deg = cnt[v], start = rowstart[v];
    float acc[16];
    #pragma unroll
    for (int i = 0; i < 16; ++i) acc[i] = 0.f;
    for (int base = 0; base < deg; base += 64) {
      int m = min(deg - base, 64);
      int idx = (l < m) ? sorted[start + base + l] : 0;
      int full = m & ~7;
      for (int j = 0; j < full; j += 8) {
        int d = __shfl(idx, j + g, 64);            // uniform trip count: safe
        uint4 u = mu8[(size_t)d*8 + c];
        fp8acc(acc, u.x, 0); fp8acc(acc, u.y, 4);
        fp8acc(acc, u.z, 8); fp8acc(acc, u.w, 12);
      }
      int rem = m - full;
      if (rem) {                                   // WAVE-UNIFORM branch
        int d = __shfl(idx, full + min(g, rem-1), 64);  // all 64 lanes execute
        if (g < rem) {                             // predicate load+accumulate
          uint4 u = mu8[(size_t)d*8 + c];
          fp8acc(acc, u.x, 0); fp8acc(acc, u.y, 4);
          fp8acc(acc, u.z, 8); fp8acc(acc, u.w, 12);
        }
      }
    }
    uint um = mu_u[(size_t)v*64 + l];              // hoisted: hides under bfly
    #pragma unroll
    for (int i = 0; i < 16; ++i) {
      acc[i] += __shfl_xor(acc[i], 8, 64);
      acc[i] += __shfl_xor(acc[i], 16, 64);
      acc[i] += __shfl_xor(acc[i], 32, 64);
    }
    // all lanes now hold the full sums (xor-butterfly is lane-symmetric).
    // lane l owns rs word l = g*8+c: needs acc[g] and acc[g+8].
    float a01 = (g & 1) ? acc[1] : acc[0];
    float a23 = (g & 1) ? acc[3] : acc[2];
    float a45 = (g & 1) ? acc[5] : acc[4];
    float a67 = (g & 1) ? acc[7] : acc[6];
    float b01 = (g & 1) ? acc[9]  : acc[8];
    float b23 = (g & 1) ? acc[11] : acc[10];
    float b45 = (g & 1) ? acc[13] : acc[12];
    float b67 = (g & 1) ? acc[15] : acc[14];
    float a03 = (g & 2) ? a23 : a01;
    float a47 = (g & 2) ? a67 : a45;
    float b03 = (g & 2) ? b23 : b01;
    float b47 = (g & 2) ? b67 : b45;
    float alo = (g & 4) ? a47 : a03;
    float ahi = (g & 4) ? b47 : b03;
    float m0 = bflo(um), m1 = bfhi(um);
    float dg = (float)deg;
    float s0 = fmaxf(dg*m0 - alo, 0.f);
    float s1 = fmaxf(dg*m1 - ahi, 0.f);
    rs_u[(size_t)v*64 + l] = pack2(s0, s1);         // coalesced 256 B/node
    cm0 += m0; cm1 += m1;
    cr0 += s0; cr1 += s1;
  }
  // block colsum reduce (layout matches the removed k_colsum)
  ls[w*256 + 2*l]         = cm0;
  ls[w*256 + 2*l + 1]     = cm1;
  ls[w*256 + 128 + 2*l]   = cr0;
  ls[w*256 + 128 + 2*l+1] = cr1;
  __syncthreads();
  int tid = threadIdx.x;
  part[(size_t)blockIdx.x*256 + tid] =
      ls[tid] + ls[256+tid] + ls[512+tid] + ls[768+tid];
}

// ---------------------------------------------------------------------------
// FUSED k_red + k_upC (last-block pattern, proven round 12): fold
// part[GGRID][256] -> part2[REDB][256]; the LAST block runs the upC matvec
// chain and writes Cbuf. Fold order and upC arithmetic identical to the
// deleted kernels -> C is bit-identical. ctr[0] zeroed by k_mu.
// ---------------------------------------------------------------------------
__global__ __launch_bounds__(256) void k_redC(const float* __restrict__ part,
    float* __restrict__ part2, const float* __restrict__ hth,
    const float* __restrict__ th4, const float* __restrict__ th3,
    float* __restrict__ Cbuf, int* __restrict__ ctr)
{
  __shared__ int isLast;
  __shared__ float Q[256];
  __shared__ float S[128];
  __shared__ float pr[128];
  const int t = threadIdx.x, b = blockIdx.x;
  const int rpb = GGRID / REDB;
  float s = 0.f;
  for (int r = b*rpb; r < b*rpb + rpb; ++r) s += part[(size_t)r*256 + t];
  part2[(size_t)b*256 + t] = s;
  __threadfence();                       // release part2 before counting in
  __syncthreads();
  if (t == 0) isLast = (atomicAdd(ctr, 1) == REDB - 1);
  __syncthreads();
  if (!isLast) return;
  __threadfence();                       // acquire: see all part2 writes
  // ---- upC (identical arithmetic to the old k_upC, npart = REDB) ----
  if (t < 128) {
    float q0 = 0.f, q1 = 0.f;
    for (int bb = 0; bb < REDB; ++bb) {
      q0 += part2[(size_t)bb*256 + t];
      q1 += part2[(size_t)bb*256 + 128 + t];
    }
    Q[t] = q0; Q[128 + t] = q1;
  }
  __syncthreads();
  if (t < 128) {
    float gs = 0.f;
    const float4* hr = (const float4*)(hth + t*256);
    const float4* Q4 = (const float4*)Q;
    #pragma unroll 8
    for (int k = 0; k < 64; ++k) {
      float4 a = hr[k], bq = Q4[k];
      gs += a.x*bq.x + a.y*bq.y + a.z*bq.z + a.w*bq.w;
    }
    S[t] = gs;
  }
  __syncthreads();
  if (t < 128) {
    float up = 0.f;
    const float4* r4 = (const float4*)(th4 + t*128);
    const float4* S4 = (const float4*)S;
    #pragma unroll 8
    for (int k = 0; k < 32; ++k) {
      float4 a = r4[k], bs = S4[k];
      up += a.x*bs.x + a.y*bs.y + a.z*bs.z + a.w*bs.w;
    }
    pr[t] = th3[t] * fmaxf(up, 0.f);
  }
  __syncthreads();
  if (t < 64) pr[t] += pr[t + 64];
  __syncthreads();
  if (t < 64) {
    float v = pr[t];
    #pragma unroll
    for (int off = 32; off > 0; off >>= 1) v += __shfl_down(v, off, 64);
    if (t == 0) Cbuf[0] = v;
  }
}

// ---------------------------------------------------------------------------
// MFMA GEMM #2 (merged mlp+final): down_v = M2 @ [mu;rs]_v  (K=256),
// out[v] = C + sum_p th3[128+p]*relu(down_v[p]).  mu' never materialized.
// ---------------------------------------------------------------------------
__global__ __launch_bounds__(256) void k_out(
    const uint4* __restrict__ mu4, const uint4* __restrict__ rs4,
    const float* __restrict__ M2, const float* __restrict__ th3,
    const float* __restrict__ Cbuf, float* __restrict__ out, int n)
{
  __shared__ uint4 B[4096];   // [s:8][t:8][lane:64], 64 KB
  const int tid = threadIdx.x;
  for (int f = tid; f < 4096; f += 256) {
    int l = f & 63, rest = f >> 6;          // 0..63
    int s = rest >> 3, t = rest & 7;
    int row = t*16 + (l & 15);
    int kb  = s*32 + (l >> 4)*8;
    const float* p = M2 + row*256 + kb;
    float4 a = *(const float4*)p;
    float4 b = *(const float4*)(p + 4);
    uint4 u; u.x = pack2(a.x,a.y); u.y = pack2(a.z,a.w);
    u.z = pack2(b.x,b.y); u.w = pack2(b.z,b.w);
    B[(s*8 + t)*64 + l] = u;
  }
  __syncthreads();
  const int w = tid >> 6, l = tid & 63, q = l >> 4, c = l & 15;
  float t3w[8];
  #pragma unroll
  for (int t = 0; t < 8; ++t) t3w[t] = th3[128 + t*16 + c];
  const float C = Cbuf[0];
  const int ntiles = (n + 15) >> 4;
  for (int T = blockIdx.x*4 + w; T < ntiles; T += gridDim.x*4) {
    int v0 = T*16;
    int arow = min(v0 + c, n-1);
    U4H8 a[8];
    #pragma unroll
    for (int s = 0; s < 4; ++s) a[s].u   = mu4[(size_t)arow*16 + s*4 + q];
    #pragma unroll
    for (int s = 0; s < 4; ++s) a[4+s].u = rs4[(size_t)arow*16 + s*4 + q];
    f32x4 acc[8];
    #pragma unroll
    for (int t = 0; t < 8; ++t) acc[t] = (f32x4){0.f,0.f,0.f,0.f};
    #pragma unroll
    for (int s = 0; s < 8; ++s) {
      #pragma unroll
      for (int t = 0; t < 8; ++t) {
        U4H8 b; b.u = B[(s*8 + t)*64 + l];
        acc[t] = __builtin_amdgcn_mfma_f32_16x16x32_bf16(a[s].h, b.h, acc[t], 0, 0, 0);
      }
    }
    float red[4] = {0.f, 0.f, 0.f, 0.f};
    #pragma unroll
    for (int t = 0; t < 8; ++t) {
      #pragma unroll
      for (int r = 0; r < 4; ++r)
        red[r] += t3w[t] * fmaxf(acc[t][r], 0.f);
    }
    #pragma unroll
    for (int r = 0; r < 4; ++r) {
      #pragma unroll
      for (int off = 1; off < 16; off <<= 1)
        red[r] += __shfl_xor(red[r], off, 64);
    }
    if (c == 0) {
      #pragma unroll
      for (int r = 0; r < 4; ++r) {
        int node = v0 + q*4 + r;
        if (node < n) out[node] = C + red[r];
      }
    }
  }
}

extern "C" void kernel_launch(void* const* d_in, const int* in_sizes, int n_in,
                              void* d_out, int out_size, void* d_ws, size_t ws_size,
                              hipStream_t stream)
{
  const float* sv  = (const float*)d_in[0];
  const float* tv  = (const float*)d_in[1];
  const float* x   = (const float*)d_in[2];
  const int*   esrc= (const int*)d_in[3];
  const int*   edst= (const int*)d_in[4];
  const float* th1 = (const float*)d_in[5];
  const float* th2 = (const float*)d_in[6];
  const float* th3 = (const float*)d_in[7];
  const float* th4 = (const float*)d_in[8];
  const float* th5 = (const float*)d_in[9];
  const float* hth = (const float*)d_in[10];
  float* out = (float*)d_out;
  const int n = in_sizes[0];
  const int e = in_sizes[3];

  const int nblk  = (e + CHUNK - 1) / CHUNK;     // 391 partition blocks
  const int nbuck = (n + 511) >> 9;              // 196 buckets

  char* wp = (char*)d_ws;
  auto carve = [&](size_t bytes) { char* p = wp; wp += (bytes + 255) & ~(size_t)255; return p; };
  // R1 (25.6 MB): [0, e*4) = packed (k_part..k_csr);
  //               [n*128, 2*n*128) = mu8 fp8 (k_mu..k_gather)   [disjoint]
  char*   R1    = (char*) carve((size_t)n*128*2);
  ushort* mu_s  = (ushort*)carve((size_t)n*128*2);  // mu bf16 row-major (exact)
  ushort* rs_s  = (ushort*)carve((size_t)n*128*2);  // relu(s) bf16 row-major
  int*    sorted= (int*)   carve((size_t)e*4);
  int*    cnt   = (int*)   carve((size_t)n*4);
  int*    rowst = (int*)   carve((size_t)n*4);
  int*    histG = (int*)   carve((size_t)256*nblk*4);
  int*    btot  = (int*)   carve(256*4);
  int*    bbase = (int*)   carve(256*4);
  float*  M2    = (float*) carve(128*256*4);
  float*  part  = (float*) carve((size_t)GGRID*256*4);  // 2 MB gather partials
  float*  part2 = (float*) carve((size_t)REDB*256*4);
  float*  Cbuf  = (float*) carve(256);
  int*    ctr   = (int*)   carve(256);           // ctr[0]=redC, ctr[1]=scanHB

  uint*   packed= (uint*)R1;                     // lower 12.8 MB
  uint2*  mu8   = (uint2*)(R1 + (size_t)n*128);  // upper 12.8 MB

  k_mu    <<<NB_MU + nblk + 128, 256, 0, stream>>>(x, sv, tv, th1, th2, mu_s,
                                                   mu8, n, esrc, histG, e, nblk,
                                                   th5, hth, M2, ctr);
  k_scanHB<<<256, 512, 0, stream>>>(histG, btot, bbase, nblk, ctr + 1);
  k_part  <<<nblk, 512, 0, stream>>>(esrc, edst, histG, bbase, packed, e, nblk);
  k_csr   <<<nbuck, 512, 0, stream>>>(packed, btot, bbase, sorted, rowst, cnt, n);
  k_gather<<<GGRID, 256, 0, stream>>>((const uint4*)mu8, (const uint*)mu_s,
                                      sorted, cnt, rowst, (uint*)rs_s, part, n);
  k_redC  <<<REDB, 256, 0, stream>>>(part, part2, hth, th4, th3, Cbuf, ctr);
  k_out   <<<1024, 256, 0, stream>>>((const uint4*)mu_s, (const uint4*)rs_s,
                                     M2, th3, Cbuf, out, n);
}

// Round 14
// 353.189 us; speedup vs baseline: 1.0939x; 1.0939x over previous
//
#include <hip/hip_runtime.h>
#include <stdint.h>

typedef unsigned int uint;
typedef unsigned short ushort;
typedef __attribute__((ext_vector_type(4))) float f32x4;
typedef __attribute__((ext_vector_type(2))) float f32x2;
typedef __attribute__((ext_vector_type(8))) short bf16x8;   // 8 bf16 in 4 VGPRs

union U4H8 { uint4 u; bf16x8 h; };

__device__ __forceinline__ float bflo(uint u){ return __uint_as_float(u << 16); }
__device__ __forceinline__ float bfhi(uint u){ return __uint_as_float(u & 0xffff0000u); }
__device__ __forceinline__ ushort f2bf(float f){
  uint u = __float_as_uint(f);
  return (ushort)((u + 0x7fffu + ((u >> 16) & 1u)) >> 16);   // RNE
}
__device__ __forceinline__ uint pack2(float lo, float hi){
  return ((uint)f2bf(hi) << 16) | (uint)f2bf(lo);
}

// Software RNE encode f32 -> fp8 e4m3fn, f >= 0 (post-relu), saturate 448.
__device__ __forceinline__ uint fp8e(float f){
  uint u = __float_as_uint(f);
  uint r = u + 0x7FFFFu + ((u >> 20) & 1u);
  uint code = (((r >> 23) - 120u) << 3) | ((r >> 20) & 7u);
  code = (code > 0x7Eu) ? 0x7Eu : code;                  // saturate at 448
  uint den = (uint)__float2int_rn(f * 512.0f);           // 2^-9 denormal grid
  return (f >= 0.015625f) ? code : den;
}

// decode 4 fp8(e4m3) bytes of w into acc[off..off+3] (HW decode is exact)
__device__ __forceinline__ void fp8acc(float* acc, uint w, int off){
  f32x2 lo = __builtin_amdgcn_cvt_pk_f32_fp8(w, false);
  f32x2 hi = __builtin_amdgcn_cvt_pk_f32_fp8(w, true);
  acc[off+0] += lo[0]; acc[off+1] += lo[1];
  acc[off+2] += hi[0]; acc[off+3] += hi[1];
}

#define CHUNK 8192          // edges per partition block
#define NB_MU 1024          // blocks doing the mu MFMA work in the fused kernel
#define GGRID 2048          // k_gather blocks (= part rows)
#define REDB  64            // k_redC blocks (GGRID/REDB rows each)

// ---------------------------------------------------------------------------
// FUSED: MFMA GEMM #1 (mu) + edge histogram + M2 = th5 @ h_theta.
// Blocks [0,NB_MU): mu; [NB_MU, NB_MU+nblk): hist; rest: M2 rows.
// Proven round 12 (353.3µs session best). LEDGER: round-13's scanHB
// last-block fusion REGRESSED +33µs (256 blocks x 512 thr of device-scope
// __threadfence on fresh histG swamps the launch saving) -> last-block
// fusion only pays for small grids (k_redC: 64 blocks, won -9µs).
// M2 block r==0 zeroes the k_redC last-block counter.
// ---------------------------------------------------------------------------
__global__ __launch_bounds__(256) void k_mu(
    const float* __restrict__ x, const float* __restrict__ sv,
    const float* __restrict__ tv, const float* __restrict__ th1,
    const float* __restrict__ th2, ushort* __restrict__ mu_s,
    uint2* __restrict__ mu8, int n,
    const int* __restrict__ esrc, int* __restrict__ histG, int e, int nblk,
    const float* __restrict__ th5, const float* __restrict__ hth,
    float* __restrict__ M2, int* __restrict__ ctr)
{
  __shared__ uint4 B[2048];   // [s:4][t:8][lane:64], 32 KB (mu branch)
  __shared__ int lh[256];     // hist branch
  __shared__ float m2row[128];// M2 branch
  const int tid = threadIdx.x;
  const int bid = blockIdx.x;

  if (bid >= NB_MU) {
    if (bid < NB_MU + nblk) {
      // ---- histogram branch (bucket = src>>9, layout [bucket][block]) ----
      const int blk = bid - NB_MU;
      lh[tid] = 0; __syncthreads();
      const int lo = blk*CHUNK, hi = min(e, lo + CHUNK);
      for (int i = lo + tid; i < hi; i += 256)
        atomicAdd(&lh[esrc[i] >> 9], 1);
      __syncthreads();
      histG[tid*nblk + blk] = lh[tid];
    } else {
      // ---- M2 branch: row r of th5 @ h_theta (128x256) ----
      const int r = bid - NB_MU - nblk;
      if (r == 0 && tid == 0) *ctr = 0;     // reset k_redC's last-block ctr
      if (tid < 128) m2row[tid] = th5[r*128 + tid];
      __syncthreads();
      float accv = 0.f;
      #pragma unroll 8
      for (int k = 0; k < 128; ++k) accv += m2row[k] * hth[k*256 + tid];
      M2[r*256 + tid] = accv;
    }
    return;
  }

  // ---- mu branch (identical math; stride NB_MU*4) ----
  for (int f = tid; f < 2048; f += 256) {
    int l = f & 63, rest = f >> 6;          // rest: 0..31
    int s = rest >> 3, t = rest & 7;
    int row = t*16 + (l & 15);              // W row (output col p)
    int kb  = s*32 + (l >> 4)*8;
    const float* p = th2 + row*128 + kb;
    float4 a = *(const float4*)p;
    float4 b = *(const float4*)(p + 4);
    uint4 u; u.x = pack2(a.x,a.y); u.y = pack2(a.z,a.w);
    u.z = pack2(b.x,b.y); u.w = pack2(b.z,b.w);
    B[(s*8 + t)*64 + l] = u;
  }
  __syncthreads();
  const int w = tid >> 6, l = tid & 63, q = l >> 4, c = l & 15;
  float2 t1[8];
  #pragma unroll
  for (int t = 0; t < 8; ++t) t1[t] = ((const float2*)th1)[t*16 + c];
  const int ntiles = (n + 15) >> 4;
  for (int T = bid*4 + w; T < ntiles; T += NB_MU*4) {
    int v0 = T*16;
    int arow = min(v0 + c, n-1);
    const float4* xr = (const float4*)(x + (size_t)arow*128);
    float4 xf[8];
    #pragma unroll
    for (int s = 0; s < 4; ++s) {
      xf[2*s]   = xr[s*8 + q*2];
      xf[2*s+1] = xr[s*8 + q*2 + 1];
    }
    float ss = 0.f;
    #pragma unroll
    for (int i = 0; i < 8; ++i)
      ss += xf[i].x*xf[i].x + xf[i].y*xf[i].y + xf[i].z*xf[i].z + xf[i].w*xf[i].w;
    ss += __shfl_xor(ss, 16, 64);
    ss += __shfl_xor(ss, 32, 64);
    float inv = (ss > 0.f) ? rsqrtf(ss) : 1.f;
    U4H8 a[4];
    #pragma unroll
    for (int s = 0; s < 4; ++s) {
      float4 u0 = xf[2*s], u1 = xf[2*s+1];
      a[s].u = make_uint4(pack2(u0.x*inv, u0.y*inv), pack2(u0.z*inv, u0.w*inv),
                          pack2(u1.x*inv, u1.y*inv), pack2(u1.z*inv, u1.w*inv));
    }
    f32x4 acc[8];
    #pragma unroll
    for (int t = 0; t < 8; ++t) acc[t] = (f32x4){0.f,0.f,0.f,0.f};
    #pragma unroll
    for (int s = 0; s < 4; ++s) {
      #pragma unroll
      for (int t = 0; t < 8; ++t) {
        U4H8 b; b.u = B[(s*8 + t)*64 + l];
        acc[t] = __builtin_amdgcn_mfma_f32_16x16x32_bf16(a[s].h, b.h, acc[t], 0, 0, 0);
      }
    }
    float svr[4], tvr[4];
    #pragma unroll
    for (int r = 0; r < 4; ++r) {
      int node = min(v0 + q*4 + r, n-1);
      svr[r] = sv[node]; tvr[r] = tv[node];
    }
    #pragma unroll
    for (int r = 0; r < 4; ++r) {
      int node = v0 + q*4 + r;
      if (node < n) {
        float mm[8];
        #pragma unroll
        for (int t = 0; t < 8; ++t) {
          mm[t] = fmaxf(acc[t][r] + t1[t].x*svr[r] + t1[t].y*tvr[r], 0.f);
          mu_s[(size_t)node*128 + t*16 + c] = f2bf(mm[t]);
        }
        uint u0 = fp8e(mm[0]) | (fp8e(mm[1]) << 8) |
                  (fp8e(mm[2]) << 16) | (fp8e(mm[3]) << 24);
        uint u1 = fp8e(mm[4]) | (fp8e(mm[5]) << 8) |
                  (fp8e(mm[6]) << 16) | (fp8e(mm[7]) << 24);
        mu8[(size_t)node*16 + c] = make_uint2(u0, u1);   // bytes c*8..c*8+7
      }
    }
  }
}

// --------------------- CSR build: 2-phase bucket partition ------------------
// bucket = src>>9. Per-block ranking via LDS histogram + scan; no global
// atomic cursors. scanB KEPT as separate 1-block kernel (r13: wide-grid
// last-block fusion regressed; r1/r2/r6/r7: in-kernel rescan failed
// containers). Round-9 direct-atomic CSR (287µs k_fill) retired.

__global__ __launch_bounds__(512) void k_scanH(int* __restrict__ histG,
    int* __restrict__ bucketTot, int nblk)
{
  __shared__ int tmp[512];
  const int b = blockIdx.x, tid = threadIdx.x;
  int v = (tid < nblk) ? histG[b*nblk + tid] : 0;
  tmp[tid] = v; __syncthreads();
  for (int off = 1; off < 512; off <<= 1) {
    int t = (tid >= off) ? tmp[tid - off] : 0;
    __syncthreads();
    tmp[tid] += t;
    __syncthreads();
  }
  if (tid < nblk) histG[b*nblk + tid] = tmp[tid] - v;   // exclusive
  if (tid == nblk - 1) bucketTot[b] = tmp[tid];
}

__global__ __launch_bounds__(256) void k_scanB(const int* __restrict__ bucketTot,
    int* __restrict__ bucketBase)
{
  __shared__ int tmp[256];
  int tid = threadIdx.x;
  int v = bucketTot[tid];
  tmp[tid] = v; __syncthreads();
  for (int off = 1; off < 256; off <<= 1) {
    int t = (tid >= off) ? tmp[tid - off] : 0;
    __syncthreads();
    tmp[tid] += t;
    __syncthreads();
  }
  bucketBase[tid] = tmp[tid] - v;
}

__global__ __launch_bounds__(512) void k_part(
    const int* __restrict__ src, const int* __restrict__ dst,
    const int* __restrict__ histG, const int* __restrict__ bucketBase,
    uint* __restrict__ packed, int e, int nblk)
{
  __shared__ int cur[256];
  const int blk = blockIdx.x, tid = threadIdx.x;
  if (tid < 256) cur[tid] = bucketBase[tid] + histG[tid*nblk + blk];
  __syncthreads();
  const int lo = blk*CHUNK, hi = min(e, lo + CHUNK);
  for (int i = lo + tid; i < hi; i += 512) {
    int s = src[i], d = dst[i];
    int pos = atomicAdd(&cur[s >> 9], 1);
    packed[pos] = ((uint)(s & 511) << 17) | (uint)d;
  }
}

__global__ __launch_bounds__(512) void k_csr(
    const uint* __restrict__ packed, const int* __restrict__ bucketTot,
    const int* __restrict__ bucketBase, int* __restrict__ sorted,
    int* __restrict__ rowstart, int* __restrict__ cnt, int n)
{
  __shared__ int lc[512];
  __shared__ int lofs[512];
  __shared__ int lcur[512];
  const int b = blockIdx.x, tid = threadIdx.x;
  const int base = bucketBase[b], tot = bucketTot[b];
  lc[tid] = 0; __syncthreads();
  for (int i = tid; i < tot; i += 512)
    atomicAdd(&lc[packed[base + i] >> 17], 1);
  __syncthreads();
  lofs[tid] = lc[tid]; __syncthreads();
  for (int off = 1; off < 512; off <<= 1) {
    int t = (tid >= off) ? lofs[tid - off] : 0;
    __syncthreads();
    lofs[tid] += t;
    __syncthreads();
  }
  int excl = lofs[tid] - lc[tid];
  int node = (b << 9) + tid;
  lcur[tid] = base + excl;
  if (node < n) { rowstart[node] = base + excl; cnt[node] = lc[tid]; }
  __syncthreads();
  for (int i = tid; i < tot; i += 512) {
    uint p = packed[base + i];
    int pos = atomicAdd(&lcur[p >> 17], 1);
    sorted[pos] = (int)(p & 0x1FFFFu);
  }
}

// ---------------------------------------------------------------------------
// Gather: rs[v] = relu(deg*mu[v] - sum_{u in N(v)} mu[u])  + FUSED colsum.
// EXACTLY the banked 79.5µs form (scalar acc[16], plain 8-edge loop): rounds
// 3 (4-deep, 96µs) and 5 (2-deep, 90µs) proved manual load ladders lose to
// the compiler's schedule of this loop. Do not restructure.
// All-lane epilogue: butterfly leaves full sums in every lane; lane l=g*8+c
// writes rs word l (static select tree) -> coalesced 256 B/node store;
// colsum accumulated per-lane, block-reduced to part[block][256].
// ---------------------------------------------------------------------------
__global__ __launch_bounds__(256) void k_gather(
    const uint4* __restrict__ mu8, const uint* __restrict__ mu_u,
    const int* __restrict__ sorted, const int* __restrict__ cnt,
    const int* __restrict__ rowstart, uint* __restrict__ rs_u,
    float* __restrict__ part, int n)
{
  __shared__ float ls[4*256];
  const int w = threadIdx.x >> 6, l = threadIdx.x & 63;
  const int g = l >> 3, c = l & 7;
  float cm0 = 0.f, cm1 = 0.f, cr0 = 0.f, cr1 = 0.f;   // colsum accumulators
  for (int v = blockIdx.x*4 + w; v < n; v += gridDim.x*4) {
    int deg = cnt[v], start = rowstart[v];
    float acc[16];
    #pragma unroll
    for (int i = 0; i < 16; ++i) acc[i] = 0.f;
    for (int base = 0; base < deg; base += 64) {
      int m = min(deg - base, 64);
      int idx = (l < m) ? sorted[start + base + l] : 0;
      int full = m & ~7;
      for (int j = 0; j < full; j += 8) {
        int d = __shfl(idx, j + g, 64);            // uniform trip count: safe
        uint4 u = mu8[(size_t)d*8 + c];
        fp8acc(acc, u.x, 0); fp8acc(acc, u.y, 4);
        fp8acc(acc, u.z, 8); fp8acc(acc, u.w, 12);
      }
      int rem = m - full;
      if (rem) {                                   // WAVE-UNIFORM branch
        int d = __shfl(idx, full + min(g, rem-1), 64);  // all 64 lanes execute
        if (g < rem) {                             // predicate load+accumulate
          uint4 u = mu8[(size_t)d*8 + c];
          fp8acc(acc, u.x, 0); fp8acc(acc, u.y, 4);
          fp8acc(acc, u.z, 8); fp8acc(acc, u.w, 12);
        }
      }
    }
    uint um = mu_u[(size_t)v*64 + l];              // hoisted: hides under bfly
    #pragma unroll
    for (int i = 0; i < 16; ++i) {
      acc[i] += __shfl_xor(acc[i], 8, 64);
      acc[i] += __shfl_xor(acc[i], 16, 64);
      acc[i] += __shfl_xor(acc[i], 32, 64);
    }
    // all lanes now hold the full sums (xor-butterfly is lane-symmetric).
    // lane l owns rs word l = g*8+c: needs acc[g] and acc[g+8].
    float a01 = (g & 1) ? acc[1] : acc[0];
    float a23 = (g & 1) ? acc[3] : acc[2];
    float a45 = (g & 1) ? acc[5] : acc[4];
    float a67 = (g & 1) ? acc[7] : acc[6];
    float b01 = (g & 1) ? acc[9]  : acc[8];
    float b23 = (g & 1) ? acc[11] : acc[10];
    float b45 = (g & 1) ? acc[13] : acc[12];
    float b67 = (g & 1) ? acc[15] : acc[14];
    float a03 = (g & 2) ? a23 : a01;
    float a47 = (g & 2) ? a67 : a45;
    float b03 = (g & 2) ? b23 : b01;
    float b47 = (g & 2) ? b67 : b45;
    float alo = (g & 4) ? a47 : a03;
    float ahi = (g & 4) ? b47 : b03;
    float m0 = bflo(um), m1 = bfhi(um);
    float dg = (float)deg;
    float s0 = fmaxf(dg*m0 - alo, 0.f);
    float s1 = fmaxf(dg*m1 - ahi, 0.f);
    rs_u[(size_t)v*64 + l] = pack2(s0, s1);         // coalesced 256 B/node
    cm0 += m0; cm1 += m1;
    cr0 += s0; cr1 += s1;
  }
  // block colsum reduce (layout matches the removed k_colsum)
  ls[w*256 + 2*l]         = cm0;
  ls[w*256 + 2*l + 1]     = cm1;
  ls[w*256 + 128 + 2*l]   = cr0;
  ls[w*256 + 128 + 2*l+1] = cr1;
  __syncthreads();
  int tid = threadIdx.x;
  part[(size_t)blockIdx.x*256 + tid] =
      ls[tid] + ls[256+tid] + ls[512+tid] + ls[768+tid];
}

// ---------------------------------------------------------------------------
// FUSED k_red + k_upC (last-block pattern, proven round 12, -9µs): fold
// part[GGRID][256] -> part2[REDB][256]; the LAST block runs the upC matvec
// chain and writes Cbuf. Small grid (64 blocks) keeps the device-fence cost
// below the launch saving (r13: 256-block variant regressed). ctr zeroed by
// k_mu. Fold order and upC arithmetic identical -> C bit-identical.
// ---------------------------------------------------------------------------
__global__ __launch_bounds__(256) void k_redC(const float* __restrict__ part,
    float* __restrict__ part2, const float* __restrict__ hth,
    const float* __restrict__ th4, const float* __restrict__ th3,
    float* __restrict__ Cbuf, int* __restrict__ ctr)
{
  __shared__ int isLast;
  __shared__ float Q[256];
  __shared__ float S[128];
  __shared__ float pr[128];
  const int t = threadIdx.x, b = blockIdx.x;
  const int rpb = GGRID / REDB;
  float s = 0.f;
  for (int r = b*rpb; r < b*rpb + rpb; ++r) s += part[(size_t)r*256 + t];
  part2[(size_t)b*256 + t] = s;
  __threadfence();                       // release part2 before counting in
  __syncthreads();
  if (t == 0) isLast = (atomicAdd(ctr, 1) == REDB - 1);
  __syncthreads();
  if (!isLast) return;
  __threadfence();                       // acquire: see all part2 writes
  // ---- upC (identical arithmetic to the old k_upC, npart = REDB) ----
  if (t < 128) {
    float q0 = 0.f, q1 = 0.f;
    for (int bb = 0; bb < REDB; ++bb) {
      q0 += part2[(size_t)bb*256 + t];
      q1 += part2[(size_t)bb*256 + 128 + t];
    }
    Q[t] = q0; Q[128 + t] = q1;
  }
  __syncthreads();
  if (t < 128) {
    float gs = 0.f;
    const float4* hr = (const float4*)(hth + t*256);
    const float4* Q4 = (const float4*)Q;
    #pragma unroll 8
    for (int k = 0; k < 64; ++k) {
      float4 a = hr[k], bq = Q4[k];
      gs += a.x*bq.x + a.y*bq.y + a.z*bq.z + a.w*bq.w;
    }
    S[t] = gs;
  }
  __syncthreads();
  if (t < 128) {
    float up = 0.f;
    const float4* r4 = (const float4*)(th4 + t*128);
    const float4* S4 = (const float4*)S;
    #pragma unroll 8
    for (int k = 0; k < 32; ++k) {
      float4 a = r4[k], bs = S4[k];
      up += a.x*bs.x + a.y*bs.y + a.z*bs.z + a.w*bs.w;
    }
    pr[t] = th3[t] * fmaxf(up, 0.f);
  }
  __syncthreads();
  if (t < 64) pr[t] += pr[t + 64];
  __syncthreads();
  if (t < 64) {
    float v = pr[t];
    #pragma unroll
    for (int off = 32; off > 0; off >>= 1) v += __shfl_down(v, off, 64);
    if (t == 0) Cbuf[0] = v;
  }
}

// ---------------------------------------------------------------------------
// MFMA GEMM #2 (merged mlp+final): down_v = M2 @ [mu;rs]_v  (K=256),
// out[v] = C + sum_p th3[128+p]*relu(down_v[p]).  mu' never materialized.
// ---------------------------------------------------------------------------
__global__ __launch_bounds__(256) void k_out(
    const uint4* __restrict__ mu4, const uint4* __restrict__ rs4,
    const float* __restrict__ M2, const float* __restrict__ th3,
    const float* __restrict__ Cbuf, float* __restrict__ out, int n)
{
  __shared__ uint4 B[4096];   // [s:8][t:8][lane:64], 64 KB
  const int tid = threadIdx.x;
  for (int f = tid; f < 4096; f += 256) {
    int l = f & 63, rest = f >> 6;          // 0..63
    int s = rest >> 3, t = rest & 7;
    int row = t*16 + (l & 15);
    int kb  = s*32 + (l >> 4)*8;
    const float* p = M2 + row*256 + kb;
    float4 a = *(const float4*)p;
    float4 b = *(const float4*)(p + 4);
    uint4 u; u.x = pack2(a.x,a.y); u.y = pack2(a.z,a.w);
    u.z = pack2(b.x,b.y); u.w = pack2(b.z,b.w);
    B[(s*8 + t)*64 + l] = u;
  }
  __syncthreads();
  const int w = tid >> 6, l = tid & 63, q = l >> 4, c = l & 15;
  float t3w[8];
  #pragma unroll
  for (int t = 0; t < 8; ++t) t3w[t] = th3[128 + t*16 + c];
  const float C = Cbuf[0];
  const int ntiles = (n + 15) >> 4;
  for (int T = blockIdx.x*4 + w; T < ntiles; T += gridDim.x*4) {
    int v0 = T*16;
    int arow = min(v0 + c, n-1);
    U4H8 a[8];
    #pragma unroll
    for (int s = 0; s < 4; ++s) a[s].u   = mu4[(size_t)arow*16 + s*4 + q];
    #pragma unroll
    for (int s = 0; s < 4; ++s) a[4+s].u = rs4[(size_t)arow*16 + s*4 + q];
    f32x4 acc[8];
    #pragma unroll
    for (int t = 0; t < 8; ++t) acc[t] = (f32x4){0.f,0.f,0.f,0.f};
    #pragma unroll
    for (int s = 0; s < 8; ++s) {
      #pragma unroll
      for (int t = 0; t < 8; ++t) {
        U4H8 b; b.u = B[(s*8 + t)*64 + l];
        acc[t] = __builtin_amdgcn_mfma_f32_16x16x32_bf16(a[s].h, b.h, acc[t], 0, 0, 0);
      }
    }
    float red[4] = {0.f, 0.f, 0.f, 0.f};
    #pragma unroll
    for (int t = 0; t < 8; ++t) {
      #pragma unroll
      for (int r = 0; r < 4; ++r)
        red[r] += t3w[t] * fmaxf(acc[t][r], 0.f);
    }
    #pragma unroll
    for (int r = 0; r < 4; ++r) {
      #pragma unroll
      for (int off = 1; off < 16; off <<= 1)
        red[r] += __shfl_xor(red[r], off, 64);
    }
    if (c == 0) {
      #pragma unroll
      for (int r = 0; r < 4; ++r) {
        int node = v0 + q*4 + r;
        if (node < n) out[node] = C + red[r];
      }
    }
  }
}

extern "C" void kernel_launch(void* const* d_in, const int* in_sizes, int n_in,
                              void* d_out, int out_size, void* d_ws, size_t ws_size,
                              hipStream_t stream)
{
  const float* sv  = (const float*)d_in[0];
  const float* tv  = (const float*)d_in[1];
  const float* x   = (const float*)d_in[2];
  const int*   esrc= (const int*)d_in[3];
  const int*   edst= (const int*)d_in[4];
  const float* th1 = (const float*)d_in[5];
  const float* th2 = (const float*)d_in[6];
  const float* th3 = (const float*)d_in[7];
  const float* th4 = (const float*)d_in[8];
  const float* th5 = (const float*)d_in[9];
  const float* hth = (const float*)d_in[10];
  float* out = (float*)d_out;
  const int n = in_sizes[0];
  const int e = in_sizes[3];

  const int nblk  = (e + CHUNK - 1) / CHUNK;     // 391 partition blocks
  const int nbuck = (n + 511) >> 9;              // 196 buckets

  char* wp = (char*)d_ws;
  auto carve = [&](size_t bytes) { char* p = wp; wp += (bytes + 255) & ~(size_t)255; return p; };
  // R1 (25.6 MB): [0, e*4) = packed (k_part..k_csr);
  //               [n*128, 2*n*128) = mu8 fp8 (k_mu..k_gather)   [disjoint]
  char*   R1    = (char*) carve((size_t)n*128*2);
  ushort* mu_s  = (ushort*)carve((size_t)n*128*2);  // mu bf16 row-major (exact)
  ushort* rs_s  = (ushort*)carve((size_t)n*128*2);  // relu(s) bf16 row-major
  int*    sorted= (int*)   carve((size_t)e*4);
  int*    cnt   = (int*)   carve((size_t)n*4);
  int*    rowst = (int*)   carve((size_t)n*4);
  int*    histG = (int*)   carve((size_t)256*nblk*4);
  int*    btot  = (int*)   carve(256*4);
  int*    bbase = (int*)   carve(256*4);
  float*  M2    = (float*) carve(128*256*4);
  float*  part  = (float*) carve((size_t)GGRID*256*4);  // 2 MB gather partials
  float*  part2 = (float*) carve((size_t)REDB*256*4);
  float*  Cbuf  = (float*) carve(256);
  int*    ctr   = (int*)   carve(256);

  uint*   packed= (uint*)R1;                     // lower 12.8 MB
  uint2*  mu8   = (uint2*)(R1 + (size_t)n*128);  // upper 12.8 MB

  k_mu    <<<NB_MU + nblk + 128, 256, 0, stream>>>(x, sv, tv, th1, th2, mu_s,
                                                   mu8, n, esrc, histG, e, nblk,
                                                   th5, hth, M2, ctr);
  k_scanH <<<256, 512, 0, stream>>>(histG, btot, nblk);
  k_scanB <<<1, 256, 0, stream>>>(btot, bbase);
  k_part  <<<nblk, 512, 0, stream>>>(esrc, edst, histG, bbase, packed, e, nblk);
  k_csr   <<<nbuck, 512, 0, stream>>>(packed, btot, bbase, sorted, rowst, cnt, n);
  k_gather<<<GGRID, 256, 0, stream>>>((const uint4*)mu8, (const uint*)mu_s,
                                      sorted, cnt, rowst, (uint*)rs_s, part, n);
  k_redC  <<<REDB, 256, 0, stream>>>(part, part2, hth, th4, th3, Cbuf, ctr);
  k_out   <<<1024, 256, 0, stream>>>((const uint4*)mu_s, (const uint4*)rs_s,
                                     M2, th3, Cbuf, out, n);
}